// Round 1
// baseline (376.245 us; speedup 1.0000x reference)
//
#include <hip/hip_runtime.h>

// Problem: B=8, C=256, H=W=64, K=3, pad=1, stride=1
// out_flat[bc*36864 + p] = kflat_bc[p] * qflat_bc[(p/9)*9 + 4]
// where p = j*4096 + l, j=kh*3+kw, l=h*64+w, value = plane[h+kh-1, w+kw-1].
//
// V2: occupancy experiment. Previous version staged BOTH planes in LDS
// (32 KB/block -> 5 blocks/CU) and likely ran >64 VGPR (-> 16 waves/CU).
// All throughput pipes modeled <60us but kernel measured ~163us -> latency
// bound. Now: only the key plane lives in LDS (16 KB); query center factors
// are gathered straight from global (16 KB plane, L1-resident, ~2-3 lines
// per wave-load). __launch_bounds__(256,8) caps VGPR at 64 -> 8 blocks/CU,
// 32 waves/CU, grid 2048 = exactly one resident pass.
#define HW 4096

// qcenter[l2] = qflat_bc[l2*9 + 4]; decompose idx -> (j4, l4) -> padded tap.
// Safe for l2 up to 4096 (speculative qb): address stays inside the plane.
static __device__ __forceinline__ float qload_g(const float* __restrict__ qp,
                                                int l2) {
    int idx = l2 * 9 + 4;
    int j4  = idx >> 12;
    int l4  = idx & 4095;
    int h4  = l4 >> 6;
    int w4  = l4 & 63;
    int jd  = (j4 * 11) >> 5;          // j4 / 3 for j4 in [0,9]
    int hh  = h4 + jd - 1;
    int ww  = w4 + (j4 - jd * 3) - 1;
    float v = 0.0f;
    if ((unsigned)hh < 64u && (unsigned)ww < 64u)
        v = qp[(hh << 6) + ww];
    return v;
}

__global__ __launch_bounds__(256, 8) void appcomp_kernel(
    const float* __restrict__ key,
    const float* __restrict__ query,
    float* __restrict__ out)
{
    __shared__ float k_s[HW];          // 16 KB only -> 8 blocks/CU fit

    const int bc  = blockIdx.x;        // 2048 blocks, one per (b,c)
    const int tid = threadIdx.x;
    const float* __restrict__ qp = query + bc * HW;

    // Phase 1: stage key plane, fully coalesced float4.
    {
        const float4* kg = (const float4*)(key + bc * HW);
        float4* k4 = (float4*)k_s;
        #pragma unroll
        for (int i = 0; i < 4; i++) {
            int idx = i * 256 + tid;
            k4[idx] = kg[idx];
        }
    }
    __syncthreads();

    // Phase 2: 36 chunks of 4 consecutive outputs per thread.
    float* oplane = out + (size_t)bc * 36864;
    #pragma unroll 2
    for (int i = 0; i < 36; i++) {
        int t  = i * 256 + tid;          // chunk id in [0, 9216)
        int r  = t << 2;                 // base p, [0, 36864)
        int j  = t >> 10;                // tap index 0..8 (wave-uniform)
        int l  = r & 4095;
        int h  = l >> 6;
        int w0 = l & 63;                 // multiple of 4

        int jd3 = (j * 11) >> 5;         // j/3
        int dh  = jd3 - 1;
        int dw  = j - jd3 * 3 - 1;       // wave-uniform
        int hh  = h + dh;

        float kf[4];
        if ((unsigned)hh < 64u) {
            const float* rowp = k_s + (hh << 6);
            float4 a = *(const float4*)(rowp + w0);      // 16B-aligned LDS
            if (dw == 0) {
                kf[0] = a.x; kf[1] = a.y; kf[2] = a.z; kf[3] = a.w;
            } else if (dw < 0) {
                kf[0] = (w0 > 0) ? rowp[w0 - 1] : 0.0f;
                kf[1] = a.x; kf[2] = a.y; kf[3] = a.z;
            } else {
                kf[0] = a.y; kf[1] = a.z; kf[2] = a.w;
                kf[3] = (w0 < 60) ? rowp[w0 + 4] : 0.0f;
            }
        } else {
            kf[0] = kf[1] = kf[2] = kf[3] = 0.0f;
        }

        // query factors: 4 consecutive p span at most two l2 = p/9 values.
        // qb loaded unconditionally (masked later; address always in-bounds).
        int l2a   = r / 9;
        int m9    = r - l2a * 9;
        int split = 9 - m9;              // [0, split) use qa, rest qb
        float qa = qload_g(qp, l2a);
        float qb = qload_g(qp, l2a + 1);

        float f[4];
        #pragma unroll
        for (int q = 0; q < 4; q++)
            f[q] = kf[q] * ((q < split) ? qa : qb);

        *(float4*)(oplane + r) = make_float4(f[0], f[1], f[2], f[3]);
    }
}

extern "C" void kernel_launch(void* const* d_in, const int* in_sizes, int n_in,
                              void* d_out, int out_size, void* d_ws, size_t ws_size,
                              hipStream_t stream) {
    const float* key   = (const float*)d_in[0];
    const float* query = (const float*)d_in[1];
    float* out = (float*)d_out;
    appcomp_kernel<<<2048, 256, 0, stream>>>(key, query, out);
}

// Round 2
// 351.910 us; speedup vs baseline: 1.0692x; 1.0692x over previous
//
#include <hip/hip_runtime.h>

// Problem: B=8, C=256, H=W=64, K=3, pad=1, stride=1
// out_flat[bc*36864 + p] = kflat_bc[p] * qc_bc[p/9]
// where p = j*4096 + l, j=kh*3+kw, l=h*64+w, kflat value = plane[h+kh-1,w+kw-1],
// and qc[l2] = qflat[l2*9+4] (the center-tap query factor).
//
// V3: revert V2 (global q gathers + VGPR squeeze regressed +23us). One change
// vs the 353us V1: precompute the 4096-entry qc table ONCE per block instead
// of decoding a q tap twice per 4-output chunk (18432 redundant decodes ->
// 4096). The qc table overwrites q_s in place (reg bounce across a barrier),
// so LDS stays 32 KB -> same 5 blocks/CU as V1. Phase-2 q path drops from
// ~26 ALU + 2 LDS to ~4 ALU + 2 LDS per chunk, cutting the per-store
// dependency chain by ~100 cycles.
#define HW 4096

__global__ __launch_bounds__(256) void appcomp_kernel(
    const float* __restrict__ key,
    const float* __restrict__ query,
    float* __restrict__ out)
{
    __shared__ float k_s[HW];
    __shared__ float q_s[HW];   // staged q plane, then overwritten with qc table

    const int bc  = blockIdx.x;          // 2048 blocks, one per (b,c)
    const int tid = threadIdx.x;

    // Phase 1: stage both planes, fully coalesced float4.
    {
        const float4* kg = (const float4*)(key + bc * HW);
        const float4* qg = (const float4*)(query + bc * HW);
        float4* k4 = (float4*)k_s;
        float4* q4 = (float4*)q_s;
        #pragma unroll
        for (int i = 0; i < 4; i++) {
            int idx = i * 256 + tid;
            k4[idx] = kg[idx];
            q4[idx] = qg[idx];
        }
    }
    __syncthreads();

    // Phase 1b: decode each center value exactly once -> registers.
    // qc[l2] = q_s[tap decode of idx = l2*9+4]; lane-stride-1 over l2 ->
    // stride-9 LDS addresses -> conflict-free (gcd(9,32)=1).
    float qc[16];
    #pragma unroll
    for (int s = 0; s < 16; s++) {
        int l2  = s * 256 + tid;
        int idx = l2 * 9 + 4;
        int j4  = idx >> 12;
        int l4  = idx & 4095;
        int h4  = l4 >> 6;
        int w4  = l4 & 63;
        int jd  = (j4 * 11) >> 5;          // j4/3 for j4 in [0,8]
        int hh  = h4 + jd - 1;
        int ww  = w4 + (j4 - jd * 3) - 1;
        qc[s] = ((unsigned)hh < 64u && (unsigned)ww < 64u)
                    ? q_s[(hh << 6) + ww] : 0.0f;
    }
    __syncthreads();   // all reads of the raw q plane done

    // Phase 1c: overwrite q_s with the qc table (stride-1 writes, no conflicts).
    #pragma unroll
    for (int s = 0; s < 16; s++)
        q_s[s * 256 + tid] = qc[s];
    __syncthreads();

    // Phase 2: 36 chunks of 4 consecutive outputs per thread.
    float* oplane = out + (size_t)bc * 36864;
    #pragma unroll 4
    for (int i = 0; i < 36; i++) {
        int t  = i * 256 + tid;          // chunk id in [0, 9216)
        int r  = t << 2;                 // base p, [0, 36864)
        int j  = t >> 10;                // tap index 0..8 (wave-uniform)
        int l  = r & 4095;
        int h  = l >> 6;
        int w0 = l & 63;                 // multiple of 4

        int jd3 = (j * 11) >> 5;         // j/3
        int dh  = jd3 - 1;
        int dw  = j - jd3 * 3 - 1;       // wave-uniform
        int hh  = h + dh;

        float kf[4];
        if ((unsigned)hh < 64u) {
            const float* rowp = k_s + (hh << 6);
            float4 a = *(const float4*)(rowp + w0);      // 16B-aligned LDS
            if (dw == 0) {
                kf[0] = a.x; kf[1] = a.y; kf[2] = a.z; kf[3] = a.w;
            } else if (dw < 0) {
                kf[0] = (w0 > 0) ? rowp[w0 - 1] : 0.0f;
                kf[1] = a.x; kf[2] = a.y; kf[3] = a.z;
            } else {
                kf[0] = a.y; kf[1] = a.z; kf[2] = a.w;
                kf[3] = (w0 < 60) ? rowp[w0 + 4] : 0.0f;
            }
        } else {
            kf[0] = kf[1] = kf[2] = kf[3] = 0.0f;
        }

        // query factors: 4 consecutive p span at most two l2 = p/9 values.
        // qc table lookup only — no tap decode in the hot loop.
        int l2a   = r / 9;
        int m9    = r - l2a * 9;
        int split = 9 - m9;              // [0, split) use qa, rest qb
        int l2b   = l2a + 1;
        if (l2b > 4095) l2b = 4095;      // qb unused when l2a==4095; keep read in-bounds
        float qa = q_s[l2a];
        float qb = q_s[l2b];

        float f[4];
        #pragma unroll
        for (int q = 0; q < 4; q++)
            f[q] = kf[q] * ((q < split) ? qa : qb);

        *(float4*)(oplane + r) = make_float4(f[0], f[1], f[2], f[3]);
    }
}

extern "C" void kernel_launch(void* const* d_in, const int* in_sizes, int n_in,
                              void* d_out, int out_size, void* d_ws, size_t ws_size,
                              hipStream_t stream) {
    const float* key   = (const float*)d_in[0];
    const float* query = (const float*)d_in[1];
    float* out = (float*)d_out;
    appcomp_kernel<<<2048, 256, 0, stream>>>(key, query, out);
}